// Round 15
// baseline (332.439 us; speedup 1.0000x reference)
//
#include <hip/hip_runtime.h>

// Capsule dynamic routing — R21 (= R20 with compile fix): XCD-local ut +
// software-pipelined routing. u_i:(B,N,DI) f32, w:(1,N,NO,DI,DE) f32,
// bias:(N,NO,1) f32, r=3.
// Identity: logits_r = u_ji . vsum (u_ji includes bias so bias folds in).
// Evidence chain (R1-R13):
//   - Routing ~40-44us/launch invariant under weight delivery (scalar R2/R12,
//     LDS R3/R18, vector R5); register variants spill (R4/R8/R9); coop fusion
//     5x worse (R10); uji materialization BW-bound (R11). Squash ~4-5us
//     (R13) -> budget: 3.5 + 3x44 + 3x4.5 + ~30 gaps.
//   - VALUBusy 25% == 10us VALU issue / 40us wall. Shared cost of all
//     variants: per-step ut reads. ut written by transpose on ARBITRARY
//     XCDs -> routing reads are remote-L2 misses (L3/HBM, ~600-900cy);
//     routing FETCH_SIZE ~ ut+u size confirms. 2.5 waves/SIMD + runtime
//     loop can't hide ~900cy/step.
// R21: (1) transpose regridded to (128,4): block bx writes exactly routing-
//   tile bx's 9 n-rows; linear id = bx+128*by, 128%8==0 -> writer XCD ==
//   bx%8 == reader XCD (t&7): ut becomes XCD-LOCAL L2 (1.2MB/XCD, ~200cy).
//   (2) routing i-loop unroll 3 + nontemporal s_part stores (via clang
//   ext_vector float4 — HIP float4 is rejected by the builtin, R14).

#define B    256
#define N    1152
#define NO   10
#define DI   8
#define DE   16
#define NTILE   9
#define NTILES  128    // N / NTILE
#define BPT     2      // b per thread
#define BG      128    // b per block
#define BGS     2      // B / BG
#define THREADS 640    // 10 waves, o = wave id
#define GRID    (NTILES * BGS)   // 256 blocks = 1/CU

typedef float vfloat4 __attribute__((ext_vector_type(4)));

// ws layout (floats)
#define SP_OFF 0
#define SP_SZ  (NTILES * B * NO * DE)   // 5,242,880
#define VS_OFF (SP_OFF + SP_SZ)
#define VS_SZ  (B * NO * DE)            // 40,960
#define UT_OFF (VS_OFF + VS_SZ)
#define UT_SZ  (2 * N * B * 4)          // 2,359,296 (= B*N*DI)

// ---------------------------------------------------------------------------
// Transpose v2, XCD-aligned: grid (NTILES, B/64). Block (bx, by) writes the
// 9 n-rows of routing tile bx for b-range by -> lands in XCD bx%8's L2,
// which is exactly where routing tile bx runs (id&7 == bx%8).
// ut[((n*2+h)*B + b)*4 + j] = u[b][n][h*4+j]
// ---------------------------------------------------------------------------
__global__ __launch_bounds__(256)
void transpose_kernel(const float* __restrict__ u, float* __restrict__ ut) {
    const int lane = threadIdx.x & 63;
    const int wv   = threadIdx.x >> 6;           // 0..3
    const int bx   = blockIdx.x;                 // tile, 0..127
    const int b    = blockIdx.y * 64 + lane;
    for (int i = wv; i < NTILE; i += 4) {
        const int n = bx * NTILE + i;
        const float* up = u + ((size_t)b * N + n) * DI;
        const float4 a0 = *(const float4*)up;
        const float4 a1 = *(const float4*)(up + 4);
        *(float4*)(ut + ((size_t)(n * 2 + 0) * B + b) * 4) = a0;
        *(float4*)(ut + ((size_t)(n * 2 + 1) * B + b) * 4) = a1;
    }
}

// ---------------------------------------------------------------------------
// Routing pass (R18 + unroll-3 + nt stores). Grid: 256 x 640. 1 block/CU.
// Block id encodes (tile t, b-group g) with same-tile blocks on one XCD:
//   id = (t&7) + 8*((t>>3) + 16*g)
// ---------------------------------------------------------------------------
__global__ __launch_bounds__(THREADS, 3)
void routing_kernel(const float* __restrict__ u,
                    const float* __restrict__ ut,
                    const float* __restrict__ w,
                    const float* __restrict__ bias,
                    const float* __restrict__ vsum,
                    float* __restrict__ s_part,
                    const int has_v,
                    const int use_ut) {
    __shared__ float wt[NTILE * NO * DI * DE];  // 46,080 B weight tile
    __shared__ float lgx[2][NO][BG];            // 10 KB double-buffered exchange
    const int tid  = threadIdx.x;
    const int lane = tid & 63;
    const int wv   = __builtin_amdgcn_readfirstlane(tid >> 6);  // 0..9, uniform
    const int o    = wv;                         // one output capsule per wave

    const int id   = blockIdx.x;
    const int xcd  = id & 7;
    const int sg   = id >> 3;                    // 0..31
    const int g    = sg >> 4;                    // 0..1  (b-group)
    const int t    = ((sg & 15) << 3) | xcd;     // 0..127 (tile)
    const int n0   = t * NTILE;
    const int bb   = g * BG;                     // block's b base

    // Stage the tile's weights: 11520 floats = 2880 float4, coalesced.
    {
        const float4* wg = (const float4*)(w + (size_t)n0 * NO * DI * DE);
        float4* wl = (float4*)wt;
#pragma unroll
        for (int c = 0; c < 5; ++c) {
            const int idx = c * THREADS + tid;
            if (idx < (NTILE * NO * DI * DE) / 4)
                wl[idx] = wg[idx];
        }
    }

    // Bias for this wave's o, all 9 n of the tile (scalar path, tiny).
    float bvs[NTILE];
#pragma unroll
    for (int i = 0; i < NTILE; ++i)
        bvs[i] = bias[(n0 + i) * NO + o];

    // vsum fragments for this thread's 2 b values — loop-invariant
    float4 vv[BPT][4];
#pragma unroll
    for (int bi = 0; bi < BPT; ++bi)
#pragma unroll
        for (int eq = 0; eq < 4; ++eq)
            vv[bi][eq] = make_float4(0.f, 0.f, 0.f, 0.f);
    if (has_v) {
#pragma unroll
        for (int bi = 0; bi < BPT; ++bi)
#pragma unroll
            for (int eq = 0; eq < 4; ++eq)
                vv[bi][eq] = *(const float4*)(vsum +
                    ((size_t)(bb + bi * 64 + lane) * NO + o) * DE + eq * 4);
    }

    float4 acc[BPT][4];
#pragma unroll
    for (int bi = 0; bi < BPT; ++bi)
#pragma unroll
        for (int eq = 0; eq < 4; ++eq)
            acc[bi][eq] = make_float4(0.f, 0.f, 0.f, 0.f);

    __syncthreads();   // weights staged

#pragma unroll 3
    for (int i = 0; i < NTILE; ++i) {
        const int n = n0 + i;

        // u rows for this thread's 2 b — XCD-local L2 from ut, or gather
        float ur[BPT][DI];
#pragma unroll
        for (int bi = 0; bi < BPT; ++bi) {
            const int b = bb + bi * 64 + lane;
            float4 u0, u1;
            if (use_ut) {
                const float* up = ut + ((size_t)(n * 2) * B + b) * 4;
                u0 = *(const float4*)up;
                u1 = *(const float4*)(up + B * 4);
            } else {
                const float* up = u + ((size_t)b * N + n) * DI;
                u0 = *(const float4*)up;
                u1 = *(const float4*)(up + 4);
            }
            ur[bi][0] = u0.x; ur[bi][1] = u0.y; ur[bi][2] = u0.z; ur[bi][3] = u0.w;
            ur[bi][4] = u1.x; ur[bi][5] = u1.y; ur[bi][6] = u1.z; ur[bi][7] = u1.w;
        }

        // u_ji for this wave's o, both b — weights from LDS (uniform-address
        // ds_read_b128 broadcasts, conflict-free).
        const float* wrow = wt + (i * NO + o) * (DI * DE);
        const float bv = bvs[i];
        float4 uji[BPT][4];
#pragma unroll
        for (int bi = 0; bi < BPT; ++bi)
#pragma unroll
            for (int eq = 0; eq < 4; ++eq)
                uji[bi][eq] = make_float4(bv, bv, bv, bv);
#pragma unroll
        for (int d = 0; d < DI; ++d) {
#pragma unroll
            for (int eq = 0; eq < 4; ++eq) {
                const float4 w4 = *(const float4*)(wrow + d * DE + eq * 4);
#pragma unroll
                for (int bi = 0; bi < BPT; ++bi) {
                    uji[bi][eq].x += ur[bi][d] * w4.x;
                    uji[bi][eq].y += ur[bi][d] * w4.y;
                    uji[bi][eq].z += ur[bi][d] * w4.z;
                    uji[bi][eq].w += ur[bi][d] * w4.w;
                }
            }
        }

        float c[BPT];
        if (has_v) {
            const int pb = i & 1;
            // logits: full-e dot in-thread, exchange via LDS for the softmax
#pragma unroll
            for (int bi = 0; bi < BPT; ++bi) {
                float lg = 0.f;
#pragma unroll
                for (int eq = 0; eq < 4; ++eq)
                    lg += uji[bi][eq].x * vv[bi][eq].x + uji[bi][eq].y * vv[bi][eq].y
                        + uji[bi][eq].z * vv[bi][eq].z + uji[bi][eq].w * vv[bi][eq].w;
                lgx[pb][o][bi * 64 + lane] = lg;
            }
            __syncthreads();
#pragma unroll
            for (int bi = 0; bi < BPT; ++bi) {
                float l[NO];
#pragma unroll
                for (int oo = 0; oo < NO; ++oo) l[oo] = lgx[pb][oo][bi * 64 + lane];
                float m = l[0];
#pragma unroll
                for (int oo = 1; oo < NO; ++oo) m = fmaxf(m, l[oo]);
                float sum = 0.f;
#pragma unroll
                for (int oo = 0; oo < NO; ++oo) { l[oo] = __expf(l[oo] - m); sum += l[oo]; }
                c[bi] = l[o] / sum;
            }
            // no second barrier: buffer pb next written at i+2, separated by
            // the barrier at i+1.
        } else {
            c[0] = 0.1f; c[1] = 0.1f;   // softmax of zeros
        }

#pragma unroll
        for (int bi = 0; bi < BPT; ++bi)
#pragma unroll
            for (int eq = 0; eq < 4; ++eq) {
                acc[bi][eq].x += c[bi] * uji[bi][eq].x;
                acc[bi][eq].y += c[bi] * uji[bi][eq].y;
                acc[bi][eq].z += c[bi] * uji[bi][eq].z;
                acc[bi][eq].w += c[bi] * uji[bi][eq].w;
            }
    }

    // s_part[tile][b][o][e] — nontemporal (protect ut's L2 residency).
    // clang ext_vector type: HIP float4 is rejected by the builtin (R14).
#pragma unroll
    for (int bi = 0; bi < BPT; ++bi) {
        float* sp = s_part + (((size_t)t * B + bb + bi * 64 + lane) * NO + o) * DE;
#pragma unroll
        for (int eq = 0; eq < 4; ++eq) {
            vfloat4 v;
            v.x = acc[bi][eq].x; v.y = acc[bi][eq].y;
            v.z = acc[bi][eq].z; v.w = acc[bi][eq].w;
            __builtin_nontemporal_store(v, (vfloat4*)(sp + eq * 4));
        }
    }
}

// ---------------------------------------------------------------------------
// Squash v2 (R13, proven bit-identical): float4-coalesced.
// Grid 640 x 64 (exactly 4*B*NO*DE/4 items).
// ---------------------------------------------------------------------------
__global__ __launch_bounds__(64)
void squash_kernel(const float* __restrict__ s_part,
                   float* __restrict__ vsum,
                   float* __restrict__ out,
                   const int accum) {
    const int idx = blockIdx.x * 64 + threadIdx.x;   // < 40960
    const int q   = idx & 3;                         // tile quarter
    const int g4  = idx >> 2;                        // float4 index, < 10240

    float4 s4 = make_float4(0.f, 0.f, 0.f, 0.f);
    const float4* sp = (const float4*)s_part
                     + (size_t)(q * 32) * (B * NO * DE / 4) + g4;
#pragma unroll 8
    for (int i = 0; i < 32; ++i) {
        const float4 v = sp[(size_t)i * (B * NO * DE / 4)];
        s4.x += v.x; s4.y += v.y; s4.z += v.z; s4.w += v.w;
    }
    // cross-q reduce (xor 1 then 2 — same tree as v1)
    s4.x += __shfl_xor(s4.x, 1); s4.y += __shfl_xor(s4.y, 1);
    s4.z += __shfl_xor(s4.z, 1); s4.w += __shfl_xor(s4.w, 1);
    s4.x += __shfl_xor(s4.x, 2); s4.y += __shfl_xor(s4.y, 2);
    s4.z += __shfl_xor(s4.z, 2); s4.w += __shfl_xor(s4.w, 2);

    // ||s||^2 for this (b,o): 4 float4s live on lanes differing in bits 2-3
    float nsq = s4.x * s4.x + s4.y * s4.y + s4.z * s4.z + s4.w * s4.w;
    nsq += __shfl_xor(nsq, 4);
    nsq += __shfl_xor(nsq, 8);

    const float nrm   = sqrtf(nsq);
    const float scale = nrm / (1.f + nsq);
    const float4 val  = make_float4(s4.x * scale, s4.y * scale,
                                    s4.z * scale, s4.w * scale);

    if (q == 0) {
        ((float4*)out)[g4] = val;                    // (B,NO,DE)
        if (accum) {
            const float4 vo = ((const float4*)vsum)[g4];
            ((float4*)vsum)[g4] = make_float4(vo.x + val.x, vo.y + val.y,
                                              vo.z + val.z, vo.w + val.w);
        } else {
            ((float4*)vsum)[g4] = val;
        }
    }
}

extern "C" void kernel_launch(void* const* d_in, const int* in_sizes, int n_in,
                              void* d_out, int out_size, void* d_ws, size_t ws_size,
                              hipStream_t stream) {
    const float* u    = (const float*)d_in[0];
    const float* w    = (const float*)d_in[1];   // (N,NO,DI,DE)
    const float* bias = (const float*)d_in[2];   // (N,NO)
    // d_in[3] = r, static 3

    float* wsf    = (float*)d_ws;
    float* s_part = wsf + SP_OFF;
    float* vsum   = wsf + VS_OFF;
    float* ut     = wsf + UT_OFF;
    float* out    = (float*)d_out;

    const int use_ut = (ws_size >= (size_t)(SP_SZ + VS_SZ + UT_SZ) * sizeof(float));

    if (use_ut)
        transpose_kernel<<<dim3(NTILES, B / 64), 256, 0, stream>>>(u, ut);

    for (int it = 0; it < 3; ++it) {
        routing_kernel<<<GRID, THREADS, 0, stream>>>(
            u, ut, w, bias, vsum, s_part, it > 0, use_ut);
        squash_kernel<<<(B * NO * DE) / 64, 64, 0, stream>>>(
            s_part, vsum, out, it > 0);
    }
}

// Round 16
// 182.126 us; speedup vs baseline: 1.8253x; 1.8253x over previous
//
#include <hip/hip_runtime.h>

// Capsule dynamic routing — R22: R18 routing (byte-identical, proven 181.1us)
// + squash v2 + XCD-ALIGNED transpose (the only untested clean component of
// R20/R21; unroll-3 and nt-stores both spilled — R15).
// u_i:(B,N,DI) f32, w:(1,N,NO,DI,DE) f32, bias:(N,NO,1) f32, r=3.
// Identity: logits_r = u_ji . vsum (u_ji includes bias so bias folds in).
// Evidence chain (R1-R15):
//   - Routing ~40-44us/launch invariant under weight delivery (scalar R2/R12,
//     LDS R3/R18, vector R5). ANY added live state spills (R4/R8/R9/R15:
//     WRITE_SIZE 150-220MB, VGPR pinned 84). Coop fusion 5x worse (R10).
//     uji materialization BW-bound (R11). Squash ~4-5us (R13).
//   - Remaining untested lever: ut written on arbitrary XCDs -> routing's
//     per-step reads are remote-L2/L3 (~600-900cy, unhidable at 2.5 w/SIMD).
//     Transpose regrid (128,4): block bx writes tile bx's rows; 128%8==0 ->
//     writer XCD == bx%8 == reader XCD. Zero routing-codegen risk.
// Diagnostic: FETCH 8.4->2-4MB = theory confirmed; no change = plateau
// declared next round.

#define B    256
#define N    1152
#define NO   10
#define DI   8
#define DE   16
#define NTILE   9
#define NTILES  128    // N / NTILE
#define BPT     2      // b per thread
#define BG      128    // b per block
#define BGS     2      // B / BG
#define THREADS 640    // 10 waves, o = wave id
#define GRID    (NTILES * BGS)   // 256 blocks = 1/CU

// ws layout (floats)
#define SP_OFF 0
#define SP_SZ  (NTILES * B * NO * DE)   // 5,242,880
#define VS_OFF (SP_OFF + SP_SZ)
#define VS_SZ  (B * NO * DE)            // 40,960
#define UT_OFF (VS_OFF + VS_SZ)
#define UT_SZ  (2 * N * B * 4)          // 2,359,296 (= B*N*DI)

// ---------------------------------------------------------------------------
// Transpose, XCD-aligned: grid (NTILES, B/64). Block (bx, by) writes the
// 9 n-rows of routing tile bx for b-range by -> lands in XCD bx%8's L2,
// which is where routing tile bx runs (id&7 == bx%8).
// ut[((n*2+h)*B + b)*4 + j] = u[b][n][h*4+j]
// ---------------------------------------------------------------------------
__global__ __launch_bounds__(256)
void transpose_kernel(const float* __restrict__ u, float* __restrict__ ut) {
    const int lane = threadIdx.x & 63;
    const int wv   = threadIdx.x >> 6;           // 0..3
    const int bx   = blockIdx.x;                 // tile, 0..127
    const int b    = blockIdx.y * 64 + lane;
    for (int i = wv; i < NTILE; i += 4) {
        const int n = bx * NTILE + i;
        const float* up = u + ((size_t)b * N + n) * DI;
        const float4 a0 = *(const float4*)up;
        const float4 a1 = *(const float4*)(up + 4);
        *(float4*)(ut + ((size_t)(n * 2 + 0) * B + b) * 4) = a0;
        *(float4*)(ut + ((size_t)(n * 2 + 1) * B + b) * 4) = a1;
    }
}

// ---------------------------------------------------------------------------
// Routing pass (R18, byte-identical — proven clean codegen, 181.1us total).
// Grid: 256 x 640. 1 block/CU. Block id encodes (tile t, b-group g) with
// same-tile blocks on one XCD: id = (t&7) + 8*((t>>3) + 16*g)
// ---------------------------------------------------------------------------
__global__ __launch_bounds__(THREADS, 3)
void routing_kernel(const float* __restrict__ u,
                    const float* __restrict__ ut,
                    const float* __restrict__ w,
                    const float* __restrict__ bias,
                    const float* __restrict__ vsum,
                    float* __restrict__ s_part,
                    const int has_v,
                    const int use_ut) {
    __shared__ float wt[NTILE * NO * DI * DE];  // 46,080 B weight tile
    __shared__ float lgx[2][NO][BG];            // 10 KB double-buffered exchange
    const int tid  = threadIdx.x;
    const int lane = tid & 63;
    const int wv   = __builtin_amdgcn_readfirstlane(tid >> 6);  // 0..9, uniform
    const int o    = wv;                         // one output capsule per wave

    const int id   = blockIdx.x;
    const int xcd  = id & 7;
    const int sg   = id >> 3;                    // 0..31
    const int g    = sg >> 4;                    // 0..1  (b-group)
    const int t    = ((sg & 15) << 3) | xcd;     // 0..127 (tile)
    const int n0   = t * NTILE;
    const int bb   = g * BG;                     // block's b base

    // Stage the tile's weights: 11520 floats = 2880 float4, coalesced.
    {
        const float4* wg = (const float4*)(w + (size_t)n0 * NO * DI * DE);
        float4* wl = (float4*)wt;
#pragma unroll
        for (int c = 0; c < 5; ++c) {
            const int idx = c * THREADS + tid;
            if (idx < (NTILE * NO * DI * DE) / 4)
                wl[idx] = wg[idx];
        }
    }

    // Bias for this wave's o, all 9 n of the tile (scalar path, tiny).
    float bvs[NTILE];
#pragma unroll
    for (int i = 0; i < NTILE; ++i)
        bvs[i] = bias[(n0 + i) * NO + o];

    // vsum fragments for this thread's 2 b values — loop-invariant
    float4 vv[BPT][4];
#pragma unroll
    for (int bi = 0; bi < BPT; ++bi)
#pragma unroll
        for (int eq = 0; eq < 4; ++eq)
            vv[bi][eq] = make_float4(0.f, 0.f, 0.f, 0.f);
    if (has_v) {
#pragma unroll
        for (int bi = 0; bi < BPT; ++bi)
#pragma unroll
            for (int eq = 0; eq < 4; ++eq)
                vv[bi][eq] = *(const float4*)(vsum +
                    ((size_t)(bb + bi * 64 + lane) * NO + o) * DE + eq * 4);
    }

    float4 acc[BPT][4];
#pragma unroll
    for (int bi = 0; bi < BPT; ++bi)
#pragma unroll
        for (int eq = 0; eq < 4; ++eq)
            acc[bi][eq] = make_float4(0.f, 0.f, 0.f, 0.f);

    __syncthreads();   // weights staged

    for (int i = 0; i < NTILE; ++i) {
        const int n = n0 + i;

        // u rows for this thread's 2 b — XCD-local L2 from ut, or gather
        float ur[BPT][DI];
#pragma unroll
        for (int bi = 0; bi < BPT; ++bi) {
            const int b = bb + bi * 64 + lane;
            float4 u0, u1;
            if (use_ut) {
                const float* up = ut + ((size_t)(n * 2) * B + b) * 4;
                u0 = *(const float4*)up;
                u1 = *(const float4*)(up + B * 4);
            } else {
                const float* up = u + ((size_t)b * N + n) * DI;
                u0 = *(const float4*)up;
                u1 = *(const float4*)(up + 4);
            }
            ur[bi][0] = u0.x; ur[bi][1] = u0.y; ur[bi][2] = u0.z; ur[bi][3] = u0.w;
            ur[bi][4] = u1.x; ur[bi][5] = u1.y; ur[bi][6] = u1.z; ur[bi][7] = u1.w;
        }

        // u_ji for this wave's o, both b — weights from LDS (uniform-address
        // ds_read_b128 broadcasts, conflict-free).
        const float* wrow = wt + (i * NO + o) * (DI * DE);
        const float bv = bvs[i];
        float4 uji[BPT][4];
#pragma unroll
        for (int bi = 0; bi < BPT; ++bi)
#pragma unroll
            for (int eq = 0; eq < 4; ++eq)
                uji[bi][eq] = make_float4(bv, bv, bv, bv);
#pragma unroll
        for (int d = 0; d < DI; ++d) {
#pragma unroll
            for (int eq = 0; eq < 4; ++eq) {
                const float4 w4 = *(const float4*)(wrow + d * DE + eq * 4);
#pragma unroll
                for (int bi = 0; bi < BPT; ++bi) {
                    uji[bi][eq].x += ur[bi][d] * w4.x;
                    uji[bi][eq].y += ur[bi][d] * w4.y;
                    uji[bi][eq].z += ur[bi][d] * w4.z;
                    uji[bi][eq].w += ur[bi][d] * w4.w;
                }
            }
        }

        float c[BPT];
        if (has_v) {
            const int pb = i & 1;
            // logits: full-e dot in-thread, exchange via LDS for the softmax
#pragma unroll
            for (int bi = 0; bi < BPT; ++bi) {
                float lg = 0.f;
#pragma unroll
                for (int eq = 0; eq < 4; ++eq)
                    lg += uji[bi][eq].x * vv[bi][eq].x + uji[bi][eq].y * vv[bi][eq].y
                        + uji[bi][eq].z * vv[bi][eq].z + uji[bi][eq].w * vv[bi][eq].w;
                lgx[pb][o][bi * 64 + lane] = lg;
            }
            __syncthreads();
#pragma unroll
            for (int bi = 0; bi < BPT; ++bi) {
                float l[NO];
#pragma unroll
                for (int oo = 0; oo < NO; ++oo) l[oo] = lgx[pb][oo][bi * 64 + lane];
                float m = l[0];
#pragma unroll
                for (int oo = 1; oo < NO; ++oo) m = fmaxf(m, l[oo]);
                float sum = 0.f;
#pragma unroll
                for (int oo = 0; oo < NO; ++oo) { l[oo] = __expf(l[oo] - m); sum += l[oo]; }
                c[bi] = l[o] / sum;
            }
            // no second barrier: buffer pb next written at i+2, separated by
            // the barrier at i+1.
        } else {
            c[0] = 0.1f; c[1] = 0.1f;   // softmax of zeros
        }

#pragma unroll
        for (int bi = 0; bi < BPT; ++bi)
#pragma unroll
            for (int eq = 0; eq < 4; ++eq) {
                acc[bi][eq].x += c[bi] * uji[bi][eq].x;
                acc[bi][eq].y += c[bi] * uji[bi][eq].y;
                acc[bi][eq].z += c[bi] * uji[bi][eq].z;
                acc[bi][eq].w += c[bi] * uji[bi][eq].w;
            }
    }

    // s_part[tile][b][o][e] — same layout squash expects
#pragma unroll
    for (int bi = 0; bi < BPT; ++bi) {
        float* sp = s_part + (((size_t)t * B + bb + bi * 64 + lane) * NO + o) * DE;
#pragma unroll
        for (int eq = 0; eq < 4; ++eq)
            *(float4*)(sp + eq * 4) = acc[bi][eq];
    }
}

// ---------------------------------------------------------------------------
// Squash v2 (R13, proven bit-identical): float4-coalesced.
// Grid 640 x 64 (exactly 4*B*NO*DE/4 items).
// ---------------------------------------------------------------------------
__global__ __launch_bounds__(64)
void squash_kernel(const float* __restrict__ s_part,
                   float* __restrict__ vsum,
                   float* __restrict__ out,
                   const int accum) {
    const int idx = blockIdx.x * 64 + threadIdx.x;   // < 40960
    const int q   = idx & 3;                         // tile quarter
    const int g4  = idx >> 2;                        // float4 index, < 10240

    float4 s4 = make_float4(0.f, 0.f, 0.f, 0.f);
    const float4* sp = (const float4*)s_part
                     + (size_t)(q * 32) * (B * NO * DE / 4) + g4;
#pragma unroll 8
    for (int i = 0; i < 32; ++i) {
        const float4 v = sp[(size_t)i * (B * NO * DE / 4)];
        s4.x += v.x; s4.y += v.y; s4.z += v.z; s4.w += v.w;
    }
    // cross-q reduce (xor 1 then 2 — same tree as v1)
    s4.x += __shfl_xor(s4.x, 1); s4.y += __shfl_xor(s4.y, 1);
    s4.z += __shfl_xor(s4.z, 1); s4.w += __shfl_xor(s4.w, 1);
    s4.x += __shfl_xor(s4.x, 2); s4.y += __shfl_xor(s4.y, 2);
    s4.z += __shfl_xor(s4.z, 2); s4.w += __shfl_xor(s4.w, 2);

    // ||s||^2 for this (b,o): 4 float4s live on lanes differing in bits 2-3
    float nsq = s4.x * s4.x + s4.y * s4.y + s4.z * s4.z + s4.w * s4.w;
    nsq += __shfl_xor(nsq, 4);
    nsq += __shfl_xor(nsq, 8);

    const float nrm   = sqrtf(nsq);
    const float scale = nrm / (1.f + nsq);
    const float4 val  = make_float4(s4.x * scale, s4.y * scale,
                                    s4.z * scale, s4.w * scale);

    if (q == 0) {
        ((float4*)out)[g4] = val;                    // (B,NO,DE)
        if (accum) {
            const float4 vo = ((const float4*)vsum)[g4];
            ((float4*)vsum)[g4] = make_float4(vo.x + val.x, vo.y + val.y,
                                              vo.z + val.z, vo.w + val.w);
        } else {
            ((float4*)vsum)[g4] = val;
        }
    }
}

extern "C" void kernel_launch(void* const* d_in, const int* in_sizes, int n_in,
                              void* d_out, int out_size, void* d_ws, size_t ws_size,
                              hipStream_t stream) {
    const float* u    = (const float*)d_in[0];
    const float* w    = (const float*)d_in[1];   // (N,NO,DI,DE)
    const float* bias = (const float*)d_in[2];   // (N,NO)
    // d_in[3] = r, static 3

    float* wsf    = (float*)d_ws;
    float* s_part = wsf + SP_OFF;
    float* vsum   = wsf + VS_OFF;
    float* ut     = wsf + UT_OFF;
    float* out    = (float*)d_out;

    const int use_ut = (ws_size >= (size_t)(SP_SZ + VS_SZ + UT_SZ) * sizeof(float));

    if (use_ut)
        transpose_kernel<<<dim3(NTILES, B / 64), 256, 0, stream>>>(u, ut);

    for (int it = 0; it < 3; ++it) {
        routing_kernel<<<GRID, THREADS, 0, stream>>>(
            u, ut, w, bias, vsum, s_part, it > 0, use_ut);
        squash_kernel<<<(B * NO * DE) / 64, 64, 0, stream>>>(
            s_part, vsum, out, it > 0);
    }
}